// Round 1
// baseline (1669.691 us; speedup 1.0000x reference)
//
#include <hip/hip_runtime.h>
#include <math.h>

#define NEG_INF (-__builtin_inff())

// Sizes (compile-time constants for this problem)
// B=512, S=8, U=512, D=32, G=8, DIM_IN=4096, DAG=2048
// out layout: att[512*16384] | ga[512*2048] | w[512*512*512] | outputs[512*16384]

// ---------------- K1/K2: per-split fp32 GEMM (64x64 tile, Kstep 16) ----------------
// C[b, n] = sum_k A[b, s*Ksz + k] * Bw[s][k][n - s*NS] + bias[n],  s = n / NS
__global__ __launch_bounds__(256) void gemm_split(
    const float* __restrict__ A, int lda, int Ksz,
    const float* __restrict__ Bw, int NS,
    const float* __restrict__ bias,
    float* __restrict__ C, int ldc)
{
  const int n0 = blockIdx.x * 64;
  const int b0 = blockIdx.y * 64;
  const int s  = n0 / NS;                  // 64 | NS, so split uniform per block
  const float* Bp = Bw + (size_t)s * Ksz * NS;
  const int nloc0 = n0 - s * NS;
  const int acol0 = s * Ksz;

  __shared__ float As[16][64];             // [k][row]
  __shared__ float Bs[16][64];             // [k][col]

  const int t  = threadIdx.x;
  const int tb = t & 15, tn = t >> 4;
  float acc[4][4] = {};

  for (int k0 = 0; k0 < Ksz; k0 += 16) {
    {
      int r = t & 63, g = t >> 6;          // 4 k's per thread
      float4 v = *reinterpret_cast<const float4*>(
          A + (size_t)(b0 + r) * lda + acol0 + k0 + 4 * g);
      As[4*g+0][r] = v.x; As[4*g+1][r] = v.y; As[4*g+2][r] = v.z; As[4*g+3][r] = v.w;
    }
    {
      int kk = t >> 4, n4 = t & 15;
      float4 v = *reinterpret_cast<const float4*>(
          Bp + (size_t)(k0 + kk) * NS + nloc0 + 4 * n4);
      *reinterpret_cast<float4*>(&Bs[kk][4*n4]) = v;
    }
    __syncthreads();
#pragma unroll
    for (int k = 0; k < 16; ++k) {
      float4 a4 = *reinterpret_cast<const float4*>(&As[k][4*tb]);
      float4 b4 = *reinterpret_cast<const float4*>(&Bs[k][4*tn]);
      float av[4] = {a4.x, a4.y, a4.z, a4.w};
      float bv[4] = {b4.x, b4.y, b4.z, b4.w};
#pragma unroll
      for (int i = 0; i < 4; ++i)
#pragma unroll
        for (int j = 0; j < 4; ++j)
          acc[i][j] = fmaf(av[i], bv[j], acc[i][j]);
    }
    __syncthreads();
  }
#pragma unroll
  for (int i = 0; i < 4; ++i) {
    int row = b0 + 4*tb + i;
    int col = n0 + 4*tn;
    float4 o;
    o.x = acc[i][0] + bias[col + 0];
    o.y = acc[i][1] + bias[col + 1];
    o.z = acc[i][2] + bias[col + 2];
    o.w = acc[i][3] + bias[col + 3];
    *reinterpret_cast<float4*>(C + (size_t)row * ldc + col) = o;
  }
}

// ---------------- K3: raw masked scores -> w region ----------------
// scores[b,m,u] = temp[u] * sum_d att[b,u,d]*ma[m,u,d]; mask rand<0.1 or b==m -> -inf
// Tile: 16 b x 16 m x 16 u. LDS operand layout [u][d4][b/m][4] (compute reads 2-way free).
// Epilogue transposes acc through LDS so rand reads / score writes are u-contiguous 64B.
__global__ __launch_bounds__(256) void scores_kernel(
    const float* __restrict__ att,   // [512][512][32]
    const float* __restrict__ ma,    // [512][512][32]
    const float* __restrict__ rnd,   // [512][512][512]
    const float* __restrict__ temp,  // [512]
    float* __restrict__ wout)        // [512][512][512] raw masked scores
{
  __shared__ float At[16][8][16][4];   // 32 KB
  __shared__ float Mt[16][8][16][4];   // 32 KB
  const int m0 = blockIdx.x * 16;
  const int b0 = blockIdx.y * 16;
  const int u0 = blockIdx.z * 16;
  const int t  = threadIdx.x;

  {  // stage att + ma tiles (each: 16 rows x (16u x 32d) = 2KB contiguous per row)
    int b = t >> 4;
    int base = t & 15;
    const float* srcA = att + (size_t)(b0 + b) * 16384 + u0 * 32;
    const float* srcM = ma  + (size_t)(m0 + b) * 16384 + u0 * 32;
#pragma unroll
    for (int g = 0; g < 8; ++g) {
      int i4 = base + 16 * g;            // 0..127 float4s of this row
      int ul = i4 >> 3, d4 = i4 & 7;
      float4 v = *reinterpret_cast<const float4*>(srcA + 4 * i4);
      *reinterpret_cast<float4*>(&At[ul][d4][b][0]) = v;
    }
#pragma unroll
    for (int g = 0; g < 8; ++g) {
      int i4 = base + 16 * g;
      int ul = i4 >> 3, d4 = i4 & 7;
      float4 v = *reinterpret_cast<const float4*>(srcM + 4 * i4);
      *reinterpret_cast<float4*>(&Mt[ul][d4][b][0]) = v;
    }
  }
  __syncthreads();

  const int tu = t >> 4;                 // 0..15 : u within chunk
  const int tb = t & 3;                  // 4x4 micro-tile of (b,m)
  const int tm = (t >> 2) & 3;
  float acc[4][4] = {};
#pragma unroll
  for (int d4 = 0; d4 < 8; ++d4) {
    float4 av[4], mv[4];
#pragma unroll
    for (int i = 0; i < 4; ++i)
      av[i] = *reinterpret_cast<const float4*>(&At[tu][d4][4*tb + i][0]);
#pragma unroll
    for (int j = 0; j < 4; ++j)
      mv[j] = *reinterpret_cast<const float4*>(&Mt[tu][d4][4*tm + j][0]);
#pragma unroll
    for (int i = 0; i < 4; ++i)
#pragma unroll
      for (int j = 0; j < 4; ++j) {
        acc[i][j] = fmaf(av[i].x, mv[j].x, acc[i][j]);
        acc[i][j] = fmaf(av[i].y, mv[j].y, acc[i][j]);
        acc[i][j] = fmaf(av[i].z, mv[j].z, acc[i][j]);
        acc[i][j] = fmaf(av[i].w, mv[j].w, acc[i][j]);
      }
  }
  __syncthreads();

  // transpose acc through LDS (alias At): tr[b][m][u], u-stride 17 to break banks
  float* tr = &At[0][0][0][0];           // need 16*16*17 = 4352 floats <= 8192
#pragma unroll
  for (int i = 0; i < 4; ++i)
#pragma unroll
    for (int j = 0; j < 4; ++j)
      tr[((4*tb + i) * 16 + (4*tm + j)) * 17 + tu] = acc[i][j];
  __syncthreads();

  {
    const int bl = t >> 4, ml = t & 15;
    const int gb = b0 + bl, gm = m0 + ml;
    const bool diag = (gb == gm);
    const float* rrow = rnd  + ((size_t)gb * 512 + gm) * 512 + u0;
    float*       wrow = wout + ((size_t)gb * 512 + gm) * 512 + u0;
    const float* trow = tr + (bl * 16 + ml) * 17;
#pragma unroll
    for (int q = 0; q < 4; ++q) {
      float4 rv = *reinterpret_cast<const float4*>(rrow + 4 * q);
      float rr[4] = {rv.x, rv.y, rv.z, rv.w};
      float vv[4];
#pragma unroll
      for (int e = 0; e < 4; ++e) {
        int uu = 4 * q + e;
        float v = trow[uu] * temp[u0 + uu];
        if (diag || rr[e] < 0.1f) v = NEG_INF;
        vv[e] = v;
      }
      *reinterpret_cast<float4*>(wrow + 4 * q) = make_float4(vv[0], vv[1], vv[2], vv[3]);
    }
  }
}

// ---------------- K4: in-place group softmax over memories ----------------
// For each (b, g, u): softmax over the 64 memories m = i*8+g, then /8.
// Block = (b, 32-u chunk). Stage [512][32] in 64KB LDS, XOR-swizzled on u-float4s.
__global__ __launch_bounds__(256) void softmax_kernel(float* __restrict__ w)
{
  __shared__ float sc[512 * 32];         // 64 KB
  const int u0 = blockIdx.x * 32;
  const int b  = blockIdx.y;
  const int t  = threadIdx.x;
  float* wb = w + (size_t)b * 262144;    // 512*512

  {  // stage in: 512 rows x 8 float4 = 4096 f4, 16 per thread
    int mb = t >> 3, f4 = t & 7;
#pragma unroll
    for (int g = 0; g < 16; ++g) {
      int m = mb + 32 * g;
      float4 v = *reinterpret_cast<const float4*>(wb + (size_t)m * 512 + u0 + 4 * f4);
      *reinterpret_cast<float4*>(&sc[m * 32 + ((f4 ^ (m & 7)) << 2)]) = v;
    }
  }
  __syncthreads();

  {  // softmax: thread = (g, u)
    int g = t >> 5, u = t & 31;
    int sw = (((u >> 2) ^ g) << 2) | (u & 3);   // m&7 == g for all group members
    float mx = NEG_INF;
#pragma unroll 4
    for (int i = 0; i < 64; ++i)
      mx = fmaxf(mx, sc[(i * 8 + g) * 32 + sw]);
    float sum = 0.f;
#pragma unroll 4
    for (int i = 0; i < 64; ++i) {
      float e = __expf(sc[(i * 8 + g) * 32 + sw] - mx);
      sc[(i * 8 + g) * 32 + sw] = e;
      sum += e;
    }
    float inv = 1.0f / (8.0f * sum);
#pragma unroll 4
    for (int i = 0; i < 64; ++i)
      sc[(i * 8 + g) * 32 + sw] *= inv;
  }
  __syncthreads();

  {  // write back normalized
    int mb = t >> 3, f4 = t & 7;
#pragma unroll
    for (int g = 0; g < 16; ++g) {
      int m = mb + 32 * g;
      float4 v = *reinterpret_cast<const float4*>(&sc[m * 32 + ((f4 ^ (m & 7)) << 2)]);
      *reinterpret_cast<float4*>(wb + (size_t)m * 512 + u0 + 4 * f4) = v;
    }
  }
}

// ---------------- K5: outputs[b,u,d] = sum_m w[b,m,u] * mo[m,u,d] ----------------
// Tile: 32 b x 4 u x full d=32, stream m in chunks of 16. Thread: 4b x 4d for one u.
__global__ __launch_bounds__(256) void outputs_kernel(
    const float* __restrict__ w,    // [512][512][512] normalized
    const float* __restrict__ mo,   // [512][512][32]
    float* __restrict__ out)        // [512][512][32]
{
  __shared__ float wt[16][32][4];    // [mc][b][u]  8 KB
  __shared__ float mot[16][4][32];   // [mc][u][d]  8 KB
  const int u0 = blockIdx.x * 4;
  const int b0 = blockIdx.y * 32;
  const int t  = threadIdx.x;
  const int tu = t & 3, td = (t >> 2) & 7, tb = t >> 5;   // tb 0..7 -> 4 b's each
  float acc[4][4] = {};              // [b-sub][d-sub]

  for (int mc = 0; mc < 512; mc += 16) {
    {
      int idx = t;
#pragma unroll
      for (int p = 0; p < 2; ++p, idx += 256) {
        int mm = idx & 15, bb = idx >> 4;   // bb 0..31
        float4 v = *reinterpret_cast<const float4*>(
            w + ((size_t)(b0 + bb) * 512 + mc + mm) * 512 + u0);
        *reinterpret_cast<float4*>(&wt[mm][bb][0]) = v;
      }
      int mm = t >> 4, f4 = t & 15;
#pragma unroll
      for (int p = 0; p < 2; ++p) {
        int i4 = f4 + 16 * p;               // 0..31 f4 within m's (4u x 32d) slab
        int uu = i4 >> 3, dd4 = i4 & 7;
        float4 v = *reinterpret_cast<const float4*>(
            mo + (size_t)(mc + mm) * 16384 + u0 * 32 + 4 * i4);
        *reinterpret_cast<float4*>(&mot[mm][uu][4 * dd4]) = v;
      }
    }
    __syncthreads();
#pragma unroll
    for (int m = 0; m < 16; ++m) {
      float4 mv = *reinterpret_cast<const float4*>(&mot[m][tu][4 * td]);
#pragma unroll
      for (int i = 0; i < 4; ++i) {
        float wv = wt[m][4 * tb + i][tu];
        acc[i][0] = fmaf(wv, mv.x, acc[i][0]);
        acc[i][1] = fmaf(wv, mv.y, acc[i][1]);
        acc[i][2] = fmaf(wv, mv.z, acc[i][2]);
        acc[i][3] = fmaf(wv, mv.w, acc[i][3]);
      }
    }
    __syncthreads();
  }
#pragma unroll
  for (int i = 0; i < 4; ++i) {
    float4 o = make_float4(acc[i][0], acc[i][1], acc[i][2], acc[i][3]);
    *reinterpret_cast<float4*>(
        out + ((size_t)(b0 + 4 * tb + i) * 512 + u0 + tu) * 32 + 4 * td) = o;
  }
}

extern "C" void kernel_launch(void* const* d_in, const int* in_sizes, int n_in,
                              void* d_out, int out_size, void* d_ws, size_t ws_size,
                              hipStream_t stream) {
  const float* x    = (const float*)d_in[0];   // [512][4096]
  const float* ma   = (const float*)d_in[1];   // [512][512][32]
  const float* mo   = (const float*)d_in[2];   // [512][512][32]
  const float* rnd  = (const float*)d_in[3];   // [512][512][512]
  const float* w1   = (const float*)d_in[4];   // [8][512][256]
  const float* b1   = (const float*)d_in[5];   // [8][256]
  const float* w2   = (const float*)d_in[6];   // [8][256][2048]
  const float* b2   = (const float*)d_in[7];   // [8][2048]
  const float* temp = (const float*)d_in[8];   // [512]

  float* out  = (float*)d_out;
  float* att  = out;                  // 8388608
  float* ga   = out + 8388608;        // 1048576
  float* wbuf = out + 9437184;        // 134217728
  float* outs = out + 143654912;      // 8388608

  // K1: ga[b, s*256+o] = x[b, s*512+:] . w1[s] + b1[s]
  gemm_split<<<dim3(32, 8), 256, 0, stream>>>(x, 4096, 512, w1, 256, b1, ga, 2048);
  // K2: att[b, s*2048+j] = ga[b, s*256+:] . w2[s] + b2[s]
  gemm_split<<<dim3(256, 8), 256, 0, stream>>>(ga, 2048, 256, w2, 2048, b2, att, 16384);
  // K3: raw masked scores into w region
  scores_kernel<<<dim3(32, 32, 32), 256, 0, stream>>>(att, ma, rnd, temp, wbuf);
  // K4: group softmax in place (/8)
  softmax_kernel<<<dim3(16, 512), 256, 0, stream>>>(wbuf);
  // K5: outputs
  outputs_kernel<<<dim3(128, 16), 256, 0, stream>>>(wbuf, mo, outs);
}

// Round 2
// 1158.857 us; speedup vs baseline: 1.4408x; 1.4408x over previous
//
#include <hip/hip_runtime.h>
#include <math.h>

#define NEGBIG (-1e30f)

// Sizes: B=512, S=8, U=512, D=32, G=8, DIM_IN=4096, DAG=2048
// out layout: att[512*16384] | ga[512*2048] | w[512^3] | outputs[512*16384]
// outputs region doubles as stats scratch between K3a and K3b:
//   cell (b,u) = outs + (b*512+u)*32 : [0..7]=M per group, [8..15]=1/(8L) per group.
//   Each cell is written by exactly one K3a block and read+overwritten by exactly
//   one K3b block -> no cross-block hazard; fully rewritten every call.

// ---------------- K1/K2: per-split fp32 GEMM (64x64 tile, Kstep 16) ----------------
__global__ __launch_bounds__(256) void gemm_split(
    const float* __restrict__ A, int lda, int Ksz,
    const float* __restrict__ Bw, int NS,
    const float* __restrict__ bias,
    float* __restrict__ C, int ldc)
{
  const int n0 = blockIdx.x * 64;
  const int b0 = blockIdx.y * 64;
  const int s  = n0 / NS;
  const float* Bp = Bw + (size_t)s * Ksz * NS;
  const int nloc0 = n0 - s * NS;
  const int acol0 = s * Ksz;

  __shared__ float As[16][64];
  __shared__ float Bs[16][64];

  const int t  = threadIdx.x;
  const int tb = t & 15, tn = t >> 4;
  float acc[4][4] = {};

  for (int k0 = 0; k0 < Ksz; k0 += 16) {
    {
      int r = t & 63, g = t >> 6;
      float4 v = *reinterpret_cast<const float4*>(
          A + (size_t)(b0 + r) * lda + acol0 + k0 + 4 * g);
      As[4*g+0][r] = v.x; As[4*g+1][r] = v.y; As[4*g+2][r] = v.z; As[4*g+3][r] = v.w;
    }
    {
      int kk = t >> 4, n4 = t & 15;
      float4 v = *reinterpret_cast<const float4*>(
          Bp + (size_t)(k0 + kk) * NS + nloc0 + 4 * n4);
      *reinterpret_cast<float4*>(&Bs[kk][4*n4]) = v;
    }
    __syncthreads();
#pragma unroll
    for (int k = 0; k < 16; ++k) {
      float4 a4 = *reinterpret_cast<const float4*>(&As[k][4*tb]);
      float4 b4 = *reinterpret_cast<const float4*>(&Bs[k][4*tn]);
      float av[4] = {a4.x, a4.y, a4.z, a4.w};
      float bv[4] = {b4.x, b4.y, b4.z, b4.w};
#pragma unroll
      for (int i = 0; i < 4; ++i)
#pragma unroll
        for (int j = 0; j < 4; ++j)
          acc[i][j] = fmaf(av[i], bv[j], acc[i][j]);
    }
    __syncthreads();
  }
#pragma unroll
  for (int i = 0; i < 4; ++i) {
    int row = b0 + 4*tb + i;
    int col = n0 + 4*tn;
    float4 o;
    o.x = acc[i][0] + bias[col + 0];
    o.y = acc[i][1] + bias[col + 1];
    o.z = acc[i][2] + bias[col + 2];
    o.w = acc[i][3] + bias[col + 3];
    *reinterpret_cast<float4*>(C + (size_t)row * ldc + col) = o;
  }
}

// ---------------- K3a: masked raw scores + online group stats ----------------
// block: 16b x 16u, m streamed in chunks of 8. thread: u=t&15, tb=(t>>4)&3, tm=t>>6,
// micro 4b x 2m at fixed u. Each (tm,j) owns group g=2*tm+j completely -> no merge.
// LDS: At f(u,d4,b) = u*516 + d4*64 + (b ^ ((2*d4)&15))*4   (33024 B)
//      Ma f(u,d4,m) = u*260 + d4*32 + ((m ^ d4)&7)*4        (16640 B)
__global__ __launch_bounds__(256) void scores_stats_kernel(
    const float* __restrict__ att,   // [512][512][32]
    const float* __restrict__ ma,    // [512][512][32]
    const float* __restrict__ rnd,   // [512][512][512]
    const float* __restrict__ temp,  // [512]
    float* __restrict__ wout,        // [512][512][512] raw masked scores
    float* __restrict__ stats)       // outs region base
{
  __shared__ float At[16 * 516];
  __shared__ float Ma[16 * 260];
  const int b0 = blockIdx.x * 16;
  const int u0 = blockIdx.y * 16;
  const int t  = threadIdx.x;
  const int u  = t & 15, tb = (t >> 4) & 3, tm = t >> 6;

  {  // stage att tile once
    int r = t >> 4, base = t & 15;
    const float* src = att + (size_t)(b0 + r) * 16384 + u0 * 32;
#pragma unroll
    for (int g = 0; g < 8; ++g) {
      int i4 = base + 16 * g;
      int uu = i4 >> 3, d4 = i4 & 7;
      float4 v = *reinterpret_cast<const float4*>(src + 4 * i4);
      *reinterpret_cast<float4*>(&At[uu*516 + d4*64 + (r ^ ((2*d4) & 15))*4]) = v;
    }
  }
  const float tmp = temp[u0 + u];
  float Ms[4][2], Ls[4][2];
#pragma unroll
  for (int i = 0; i < 4; ++i)
#pragma unroll
    for (int j = 0; j < 2; ++j) { Ms[i][j] = NEGBIG; Ls[i][j] = 0.f; }

  for (int m0 = 0; m0 < 512; m0 += 8) {
    float rv[4][2];                       // prefetch rand (latency hidden by stage+compute)
#pragma unroll
    for (int i = 0; i < 4; ++i)
#pragma unroll
      for (int j = 0; j < 2; ++j)
        rv[i][j] = rnd[((size_t)(b0 + 4*tb + i) * 512 + m0 + 2*tm + j) * 512 + u0 + u];
    __syncthreads();                      // previous chunk's readers done
    {  // stage 8 ma rows
      int r = t >> 5, base = t & 31;
      const float* src = ma + (size_t)(m0 + r) * 16384 + u0 * 32;
#pragma unroll
      for (int g = 0; g < 4; ++g) {
        int i4 = base + 32 * g;
        int uu = i4 >> 3, d4 = i4 & 7;
        float4 v = *reinterpret_cast<const float4*>(src + 4 * i4);
        *reinterpret_cast<float4*>(&Ma[uu*260 + d4*32 + ((r ^ d4) & 7)*4]) = v;
      }
    }
    __syncthreads();
    float acc[4][2] = {};
#pragma unroll
    for (int d4 = 0; d4 < 8; ++d4) {
      const int sw = (2*d4) & 15;
      float4 av[4], mv[2];
#pragma unroll
      for (int i = 0; i < 4; ++i)
        av[i] = *reinterpret_cast<const float4*>(&At[u*516 + d4*64 + ((4*tb+i) ^ sw)*4]);
#pragma unroll
      for (int j = 0; j < 2; ++j)
        mv[j] = *reinterpret_cast<const float4*>(&Ma[u*260 + d4*32 + (((2*tm+j) ^ d4) & 7)*4]);
#pragma unroll
      for (int i = 0; i < 4; ++i)
#pragma unroll
        for (int j = 0; j < 2; ++j) {
          acc[i][j] = fmaf(av[i].x, mv[j].x, acc[i][j]);
          acc[i][j] = fmaf(av[i].y, mv[j].y, acc[i][j]);
          acc[i][j] = fmaf(av[i].z, mv[j].z, acc[i][j]);
          acc[i][j] = fmaf(av[i].w, mv[j].w, acc[i][j]);
        }
    }
#pragma unroll
    for (int i = 0; i < 4; ++i)
#pragma unroll
      for (int j = 0; j < 2; ++j) {
        int gb = b0 + 4*tb + i, gm = m0 + 2*tm + j;
        float s = acc[i][j] * tmp;
        if (rv[i][j] < 0.1f || gb == gm) s = NEGBIG;
        wout[((size_t)gb * 512 + gm) * 512 + u0 + u] = s;
        float nm = fmaxf(Ms[i][j], s);
        Ls[i][j] = Ls[i][j] * __expf(Ms[i][j] - nm) + __expf(s - nm);
        Ms[i][j] = nm;
      }
  }
  // store stats: cell (b,u)[g] = M, [8+g] = 1/(8L)
#pragma unroll
  for (int i = 0; i < 4; ++i)
#pragma unroll
    for (int j = 0; j < 2; ++j) {
      int b = b0 + 4*tb + i, g = 2*tm + j;
      float* cell = stats + ((size_t)b * 512 + u0 + u) * 32;
      cell[g]     = Ms[i][j];
      cell[8 + g] = 1.0f / (8.0f * Ls[i][j]);
    }
}

// ---------------- K3b: w = exp(s-M)/(8L) (write) + outputs accumulation ----------------
// block: 32b x 16u, m chunks of 8.
// phase A (t -> b=t>>3, m=t&7): read raw s, e=exp(s-M)*SIL (stats in regs), write w,
//   stash e->E and mo chunk->Mo in LDS.
// phase B (t -> u=t>>4, bg=(t>>2)&3, dh=t&3): 8b x 8d register micro accumulates outputs.
__global__ __launch_bounds__(256) void emit_outputs_kernel(
    const float* __restrict__ mo,    // [512][512][32]
    float* __restrict__ w,           // in: raw scores, out: final w
    float* __restrict__ outs)        // in: stats cells, out: outputs [512][512][32]
{
  __shared__ float E[16 * 8 * 33];   // (u*8+m)*33 + b
  __shared__ float Mo[8 * 16 * 34];  // (m*16+u)*34 + d
  const int u0 = blockIdx.x * 16;
  const int b0 = blockIdx.y * 32;
  const int t  = threadIdx.x;
  const int ab = t >> 3, am = t & 7;               // phase A ids
  const int pu = t >> 4, pbg = (t >> 2) & 3, pdh = t & 3;  // phase B ids
  const int sm = t >> 5, sj = t & 31, su = sj >> 1, sh = sj & 1;  // Mo-stage ids

  float Mreg[16], Sreg[16];
  {
    const float* base = outs + ((size_t)(b0 + ab) * 512 + u0) * 32;
#pragma unroll
    for (int uu = 0; uu < 16; ++uu) {
      Mreg[uu] = base[uu * 32 + am];
      Sreg[uu] = base[uu * 32 + 8 + am];
    }
  }
  float4 acc[8][2];
#pragma unroll
  for (int i = 0; i < 8; ++i) {
    acc[i][0] = make_float4(0.f, 0.f, 0.f, 0.f);
    acc[i][1] = make_float4(0.f, 0.f, 0.f, 0.f);
  }

  for (int m0 = 0; m0 < 512; m0 += 8) {
    // ---- phase A: global loads issued before the sync ----
    float* wr = w + ((size_t)(b0 + ab) * 512 + m0 + am) * 512 + u0;
    float4 sv[4];
#pragma unroll
    for (int q = 0; q < 4; ++q) sv[q] = *reinterpret_cast<const float4*>(wr + 4*q);
    const float* msrc = mo + (size_t)(m0 + sm) * 16384 + (size_t)(u0 + su) * 32 + sh * 16;
    float4 mvk[4];
#pragma unroll
    for (int k = 0; k < 4; ++k) mvk[k] = *reinterpret_cast<const float4*>(msrc + 4*k);

    float ev[16];
#pragma unroll
    for (int q = 0; q < 4; ++q) {
      float sx[4] = {sv[q].x, sv[q].y, sv[q].z, sv[q].w};
#pragma unroll
      for (int e = 0; e < 4; ++e) {
        int uu = 4*q + e;
        float val = __expf(sx[e] - Mreg[uu]) * Sreg[uu];
        ev[uu] = val;
        sx[e] = val;
      }
      sv[q] = make_float4(sx[0], sx[1], sx[2], sx[3]);
    }
#pragma unroll
    for (int q = 0; q < 4; ++q) *reinterpret_cast<float4*>(wr + 4*q) = sv[q];

    __syncthreads();                   // previous phase B done reading E/Mo
#pragma unroll
    for (int uu = 0; uu < 16; ++uu) E[(uu*8 + am)*33 + ab] = ev[uu];
#pragma unroll
    for (int k = 0; k < 4; ++k)
      *reinterpret_cast<float4*>(&Mo[(sm*16 + su)*34 + sh*16 + 4*k]) = mvk[k];
    __syncthreads();

    // ---- phase B ----
#pragma unroll
    for (int m = 0; m < 8; ++m) {
      float4 ea = *reinterpret_cast<const float4*>(&E[(pu*8 + m)*33 + 8*pbg]);
      float4 eb = *reinterpret_cast<const float4*>(&E[(pu*8 + m)*33 + 8*pbg + 4]);
      float4 va = *reinterpret_cast<const float4*>(&Mo[(m*16 + pu)*34 + 8*pdh]);
      float4 vb = *reinterpret_cast<const float4*>(&Mo[(m*16 + pu)*34 + 8*pdh + 4]);
      float es[8] = {ea.x, ea.y, ea.z, ea.w, eb.x, eb.y, eb.z, eb.w};
#pragma unroll
      for (int i = 0; i < 8; ++i) {
        acc[i][0].x = fmaf(es[i], va.x, acc[i][0].x);
        acc[i][0].y = fmaf(es[i], va.y, acc[i][0].y);
        acc[i][0].z = fmaf(es[i], va.z, acc[i][0].z);
        acc[i][0].w = fmaf(es[i], va.w, acc[i][0].w);
        acc[i][1].x = fmaf(es[i], vb.x, acc[i][1].x);
        acc[i][1].y = fmaf(es[i], vb.y, acc[i][1].y);
        acc[i][1].z = fmaf(es[i], vb.z, acc[i][1].z);
        acc[i][1].w = fmaf(es[i], vb.w, acc[i][1].w);
      }
    }
  }
  // epilogue: overwrite stats cells with final outputs
#pragma unroll
  for (int i = 0; i < 8; ++i) {
    float* dst = outs + ((size_t)(b0 + 8*pbg + i) * 512 + u0 + pu) * 32 + 8*pdh;
    *reinterpret_cast<float4*>(dst)     = acc[i][0];
    *reinterpret_cast<float4*>(dst + 4) = acc[i][1];
  }
}

extern "C" void kernel_launch(void* const* d_in, const int* in_sizes, int n_in,
                              void* d_out, int out_size, void* d_ws, size_t ws_size,
                              hipStream_t stream) {
  const float* x    = (const float*)d_in[0];   // [512][4096]
  const float* ma   = (const float*)d_in[1];   // [512][512][32]
  const float* mo   = (const float*)d_in[2];   // [512][512][32]
  const float* rnd  = (const float*)d_in[3];   // [512][512][512]
  const float* w1   = (const float*)d_in[4];   // [8][512][256]
  const float* b1   = (const float*)d_in[5];   // [8][256]
  const float* w2   = (const float*)d_in[6];   // [8][256][2048]
  const float* b2   = (const float*)d_in[7];   // [8][2048]
  const float* temp = (const float*)d_in[8];   // [512]

  float* out  = (float*)d_out;
  float* att  = out;                  // 8388608
  float* ga   = out + 8388608;        // 1048576
  float* wbuf = out + 9437184;        // 134217728
  float* outs = out + 143654912;      // 8388608

  gemm_split<<<dim3(32, 8), 256, 0, stream>>>(x, 4096, 512, w1, 256, b1, ga, 2048);
  gemm_split<<<dim3(256, 8), 256, 0, stream>>>(ga, 2048, 256, w2, 2048, b2, att, 16384);
  // K3a: raw masked scores -> wbuf, stats -> outs region
  scores_stats_kernel<<<dim3(32, 32), 256, 0, stream>>>(att, ma, rnd, temp, wbuf, outs);
  // K3b: w finalize + outputs (overwrites stats cells at the end)
  emit_outputs_kernel<<<dim3(32, 16), 256, 0, stream>>>(mo, wbuf, outs);
}